// Round 6
// baseline (296.898 us; speedup 1.0000x reference)
//
#include <hip/hip_runtime.h>

typedef unsigned short u16;
typedef __attribute__((ext_vector_type(8))) __bf16 bf16x8;
typedef __attribute__((ext_vector_type(4))) float f32x4;
typedef __attribute__((ext_vector_type(4))) u16 u16x4;
typedef __attribute__((ext_vector_type(8))) u16 u16x8;

constexpr int S = 2048;
constexpr int H = 2048;
constexpr int NH = 16;
constexpr int HD = 128;
constexpr int M = 4096;   // B*S
constexpr float SCALE = 0.08838834764831845f;  // 1/sqrt(128)

__device__ __forceinline__ u16 f2bf(float f) {
  union { float f; unsigned u; } v; v.f = f;
  unsigned r = v.u + 0x7fffu + ((v.u >> 16) & 1u);  // RNE
  return (u16)(r >> 16);
}
__device__ __forceinline__ float bf2f(u16 u) {
  union { unsigned u; float f; } v; v.u = ((unsigned)u) << 16;
  return v.f;
}
__device__ __forceinline__ unsigned cvt_pk_bf16(float lo, float hi) {
  unsigned r;
  asm("v_cvt_pk_bf16_f32 %0, %1, %2" : "=v"(r) : "v"(lo), "v"(hi));
  return r;
}
__device__ __forceinline__ f32x4 MFMA16(bf16x8 a, bf16x8 b, f32x4 c) {
  return __builtin_amdgcn_mfma_f32_16x16x32_bf16(a, b, c, 0, 0, 0);
}

// async global->LDS, 16 bytes per lane. LDS dest must be wave-uniform base + lane*16.
__device__ __forceinline__ void gld16(const u16* g, u16* l) {
  __builtin_amdgcn_global_load_lds(
      (const __attribute__((address_space(1))) void*)g,
      (__attribute__((address_space(3))) void*)l, 16, 0, 0);
}

#define SBAR  { __builtin_amdgcn_sched_barrier(0); __builtin_amdgcn_s_barrier(); __builtin_amdgcn_sched_barrier(0); }
#define LGKM0 { asm volatile("s_waitcnt lgkmcnt(0)" ::: "memory"); __builtin_amdgcn_sched_barrier(0); }

// ---------------- fp32 -> bf16 cast (x) ----------------
__global__ __launch_bounds__(256) void cast_kernel(const float* __restrict__ in,
                                                   u16* __restrict__ out, int n) {
  int i = (blockIdx.x * 256 + threadIdx.x) * 4;
  if (i >= n) return;
  float4 v = *(const float4*)(in + i);
  u16x4 o;
  o[0] = f2bf(v.x); o[1] = f2bf(v.y); o[2] = f2bf(v.z); o[3] = f2bf(v.w);
  *(u16x4*)(out + i) = o;
}

// ---------------- 4 weight casts in one dispatch ----------------
__global__ __launch_bounds__(256) void cast4_kernel(const float* __restrict__ i0,
                                                    const float* __restrict__ i1,
                                                    const float* __restrict__ i2,
                                                    const float* __restrict__ i3,
                                                    u16* o0, u16* o1, u16* o2, u16* o3) {
  const float* in; u16* out;
  switch (blockIdx.y) {
    case 0: in = i0; out = o0; break;
    case 1: in = i1; out = o1; break;
    case 2: in = i2; out = o2; break;
    default: in = i3; out = o3; break;
  }
  int i = (blockIdx.x * 256 + threadIdx.x) * 4;
  float4 v = *(const float4*)(in + i);
  u16x4 o;
  o[0] = f2bf(v.x); o[1] = f2bf(v.y); o[2] = f2bf(v.z); o[3] = f2bf(v.w);
  *(u16x4*)(out + i) = o;
}

// ---------------- concat biases into [6144] ----------------
__global__ __launch_bounds__(256) void concat_bias_k(const float* __restrict__ bq,
                                                     const float* __restrict__ bk,
                                                     const float* __restrict__ bv,
                                                     float* __restrict__ bqkv) {
  int i = blockIdx.x * 256 + threadIdx.x;  // 0..6143
  const float* src = (i < 2048) ? bq : (i < 4096) ? bk : bv;
  bqkv[i] = src[i & 2047];
}

// ---------------- RoPE cos/sin table ----------------
__global__ __launch_bounds__(256) void rope_table_k(float* __restrict__ tab) {
  int i = blockIdx.x * 256 + threadIdx.x;
  if (i >= S * 64) return;
  int s = i >> 6, d = i & 63;
  float freq = expf(-(float)d * (9.210340371976184f / 64.f));  // 10000^(-d/64)
  float ang = (float)s * freq;
  tab[i * 2]     = cosf(ang);
  tab[i * 2 + 1] = sinf(ang);
}

// ================= fused QKV GEMM: 256x256 tile, NW=4, 8-phase (m201 geometry) =================
// A[M=4096][2048] x Wqkv[6144][2048]^T. Grid 384 = 16(M) x 24(N); N-tiles 0-7 Q, 8-15 K, 16-23 V.
// 8 waves (2M x 4N), per-wave 128x64 out; per K-tile 64 MFMA / 24 ds_read_b128 per wave.
// LDS 128 KiB (A,B x dbuf x [256][64]); chunk-XOR swizzle -> 0 conflicts.
// Stage ledger (A-half=2 ops, B=4 ops): ph1 A1h0, ph2 A1h1, ph4 B0<-u+2 + vmcnt(4);
// ph5/6 A0 halves, ph8 B1<-u+3 + vmcnt(4). Each gate retires exactly next tile's 8 ops.
// Epilogue: Q/K tiles -> bias + RoPE (pair-exchange col^64 across waves wc^1 via LDS) + bf16;
// V tiles -> bias + transposed store Vt[bh][d][s].
__global__ __launch_bounds__(512, 2) void gemm_qkv4(const u16* __restrict__ A,
                                                    const u16* __restrict__ Bw,
                                                    const float* __restrict__ bias,
                                                    const float* __restrict__ tab,
                                                    u16* __restrict__ Qb,
                                                    u16* __restrict__ Kb,
                                                    u16* __restrict__ Vt) {
  __shared__ u16 AsL[2 * 256 * 64];   // 64 KiB
  __shared__ u16 BsL[2 * 256 * 64];   // 64 KiB

  const int id = blockIdx.x;
  const int xcd = id & 7, sid = id >> 3;           // sid 0..47
  const int bx = xcd * 3 + (sid % 3);              // 0..23 (each XCD: 3-N-tile band, B-band 3MB -> L2)
  const int by = sid / 3;                          // 0..15
  const int brow = by * 256, bcol = bx * 256;
  const int sel = bcol >> 11;                      // 0=Q 1=K 2=V (tile never crosses)

  const int t = threadIdx.x;
  const int w = t >> 6, l = t & 63;
  const int wr = w >> 2, wc = w & 3;
  const int lr = l & 15, lg = l >> 4;
  const int swz = lr & 7;

  f32x4 acc[8][4] = {};
  bf16x8 af[4], b0[4], b1[4];

  const int sr = t >> 3, sj = t & 7;   // stage row (0..63) / chunk (0..7)

  auto STAGE_A = [&](int BUF, int HALF, int TILE) {
    u16* d = AsL + BUF * (256 * 64) + HALF * (128 * 64);
    const u16* sp = A + (size_t)(brow + HALF * 128) * H + TILE * 64;
    gld16(sp + (size_t)sr * H        + ((sj ^ (sr & 7)) * 8), d + t * 8);
    gld16(sp + (size_t)(64 + sr) * H + ((sj ^ (sr & 7)) * 8), d + (512 + t) * 8);
  };
  auto STAGE_B = [&](int BUF, int TILE) {
    u16* d = BsL + BUF * (256 * 64);
    const u16* sp = Bw + (size_t)bcol * H + TILE * 64;
    #pragma unroll
    for (int i = 0; i < 4; ++i)
      gld16(sp + (size_t)(i * 64 + sr) * H + ((sj ^ (sr & 7)) * 8),
            d + (i * 512 + t) * 8);
  };
  auto LDA = [&](int BUF, int KH, int MB) {
    const u16* base = AsL + BUF * (256 * 64) + (wr * 128 + MB * 16 + lr) * 64;
    #pragma unroll
    for (int i = 0; i < 4; ++i)
      af[i] = *(const bf16x8*)(base + i * (16 * 64) + (((KH * 4 + lg) ^ swz) * 8));
  };
  auto LDB = [&](int BUF, int KH, bf16x8* bb) {
    const u16* base = BsL + BUF * (256 * 64) + (wc * 64 + lr) * 64;
    #pragma unroll
    for (int n = 0; n < 4; ++n)
      bb[n] = *(const bf16x8*)(base + n * (16 * 64) + (((KH * 4 + lg) ^ swz) * 8));
  };
  auto MM = [&](int MB, bf16x8* bb) {
    __builtin_amdgcn_s_setprio(1);
    #pragma unroll
    for (int i = 0; i < 4; ++i)
      #pragma unroll
      for (int n = 0; n < 4; ++n)
        acc[MB + i][n] = MFMA16(af[i], bb[n], acc[MB + i][n]);
    __builtin_amdgcn_s_setprio(0);
  };

  // prologue: A0<-t0 (4), B0<-t0 (4), B1<-t1 (4); retire all but B1
  STAGE_A(0, 0, 0); STAGE_A(0, 1, 0);
  STAGE_B(0, 0);
  STAGE_B(1, 1);
  asm volatile("s_waitcnt vmcnt(4)" ::: "memory");
  SBAR;

  for (int J = 0; J < 16; ++J) {
    const int u = 2 * J;
    const bool more = (J < 15);
    // ---- tile u (buf0) ----
    LDA(0, 0, 0); LDB(0, 0, b0);
    STAGE_A(1, 0, u + 1);
    SBAR; LGKM0; MM(0, b0); SBAR;

    LDA(0, 0, 4);
    STAGE_A(1, 1, u + 1);
    SBAR; LGKM0; MM(4, b0); SBAR;

    LDA(0, 1, 0); LDB(0, 1, b1);
    SBAR; LGKM0; MM(0, b1); SBAR;

    LDA(0, 1, 4);
    if (more) STAGE_B(0, u + 2);
    SBAR; LGKM0; MM(4, b1);
    if (more) { asm volatile("s_waitcnt vmcnt(4)" ::: "memory"); }
    else      { asm volatile("s_waitcnt vmcnt(0)" ::: "memory"); }
    SBAR;
    // ---- tile u+1 (buf1) ----
    LDA(1, 0, 0); LDB(1, 0, b0);
    if (more) STAGE_A(0, 0, u + 2);
    SBAR; LGKM0; MM(0, b0); SBAR;

    LDA(1, 0, 4);
    if (more) STAGE_A(0, 1, u + 2);
    SBAR; LGKM0; MM(4, b0); SBAR;

    LDA(1, 1, 0); LDB(1, 1, b1);
    SBAR; LGKM0; MM(0, b1); SBAR;

    LDA(1, 1, 4);
    if (more) STAGE_B(1, u + 3);
    SBAR; LGKM0; MM(4, b1);
    if (more) { asm volatile("s_waitcnt vmcnt(4)" ::: "memory"); SBAR; }
  }

  // ================= epilogue =================
  if (sel < 2) {
    // Q/K: bias + RoPE + bf16. Pair-exchange (col ^ 64 <-> wave wc^1) via LDS.
    // lf layout: [wave][16 rows][64 cols] f32, row stride 66 (bank-spread).
    float* lf = (float*)AsL;            // 8 * 16*66 * 4B = 33 KiB < 64 KiB
    u16* Cq = sel ? Kb : Qb;
    const float scl = sel ? 1.f : SCALE;
    #pragma unroll
    for (int m = 0; m < 8; ++m) {
      __syncthreads();                  // prev chunk / main-loop LDS reads done
      float mine[4][4];
      #pragma unroll
      for (int n = 0; n < 4; ++n) {
        const float bv = bias[bcol + wc * 64 + n * 16 + lr];
        #pragma unroll
        for (int r = 0; r < 4; ++r) {
          mine[n][r] = acc[m][n][r] + bv;
          lf[w * (16 * 66) + (lg * 4 + r) * 66 + n * 16 + lr] = mine[n][r];
        }
      }
      __syncthreads();
      #pragma unroll
      for (int n = 0; n < 4; ++n) {
        const int j = n * 16 + lr;                       // d & 63
        const int hcol = ((bcol & 2047) + wc * 64 + j);
        #pragma unroll
        for (int r = 0; r < 4; ++r) {
          const int row = brow + wr * 128 + m * 16 + lg * 4 + r;
          const int s = row & (S - 1);
          float pr = lf[(w ^ 1) * (16 * 66) + (lg * 4 + r) * 66 + j];
          float2 cs = ((const float2*)tab)[s * 64 + j];
          float out = (wc & 1) ? (mine[n][r] * cs.x + pr * cs.y)
                               : (mine[n][r] * cs.x - pr * cs.y);
          Cq[(size_t)row * H + hcol] = f2bf(out * scl);
        }
      }
    }
  } else {
    // V: bias + transposed store Vt[((b*16+h)*128+d)*S + s]
    #pragma unroll
    for (int m = 0; m < 8; ++m) {
      const int row0 = brow + wr * 128 + m * 16 + lg * 4;
      #pragma unroll
      for (int n = 0; n < 4; ++n) {
        const int col = (bcol & 2047) + wc * 64 + n * 16 + lr;
        const float bv = bias[bcol + wc * 64 + n * 16 + lr];
        const int hh = col >> 7, d = col & 127;
        const int b = row0 >> 11, s0 = row0 & (S - 1);
        u16x4 pk;
        #pragma unroll
        for (int r = 0; r < 4; ++r) pk[r] = f2bf(acc[m][n][r] + bv);
        *(u16x4*)(Vt + ((size_t)((b * 16 + hh) * 128 + d)) * S + s0) = pk;
      }
    }
  }
}

// ================= out-proj GEMM (unchanged R5 structure: 256x128, NW=2) =================
template<int NW>
__device__ __forceinline__ void gemm_body(const u16* __restrict__ A,
                                          const u16* __restrict__ Bw,
                                          const float* __restrict__ bias,
                                          float* __restrict__ Cout,
                                          int brow, int bcol,
                                          u16* AsL, u16* BsL) {
  const int t = threadIdx.x;
  const int w = t >> 6, l = t & 63;
  const int wr = w >> 2, wc = w & 3;
  const int lr = l & 15, lg = l >> 4;
  const int swz = lr & 7;

  f32x4 acc[8][NW] = {};
  bf16x8 af[4], b0[NW], b1[NW];

  const int sr = t >> 3, sj = t & 7;

  auto STAGE_A = [&](int BUF, int HALF, int TILE) {
    u16* d = AsL + BUF * (256 * 64) + HALF * (128 * 64);
    const u16* sp = A + (size_t)(brow + HALF * 128) * H + TILE * 64;
    gld16(sp + (size_t)sr * H        + ((sj ^ (sr & 7)) * 8), d + t * 8);
    gld16(sp + (size_t)(64 + sr) * H + ((sj ^ (sr & 7)) * 8), d + (512 + t) * 8);
  };
  auto STAGE_B = [&](int BUF, int TILE) {
    u16* d = BsL + BUF * (NW * 64 * 64);
    const u16* sp = Bw + (size_t)bcol * H + TILE * 64;
    #pragma unroll
    for (int i = 0; i < NW; ++i)
      gld16(sp + (size_t)(i * 64 + sr) * H + ((sj ^ (sr & 7)) * 8),
            d + (i * 512 + t) * 8);
  };
  auto LDA = [&](int BUF, int KH, int MB) {
    const u16* base = AsL + BUF * (256 * 64) + (wr * 128 + MB * 16 + lr) * 64;
    #pragma unroll
    for (int i = 0; i < 4; ++i)
      af[i] = *(const bf16x8*)(base + i * (16 * 64) + (((KH * 4 + lg) ^ swz) * 8));
  };
  auto LDB = [&](int BUF, int KH, bf16x8* bb) {
    const u16* base = BsL + BUF * (NW * 64 * 64) + (wc * (NW * 16) + lr) * 64;
    #pragma unroll
    for (int n = 0; n < NW; ++n)
      bb[n] = *(const bf16x8*)(base + n * (16 * 64) + (((KH * 4 + lg) ^ swz) * 8));
  };
  auto MM = [&](int MB, bf16x8* bb) {
    __builtin_amdgcn_s_setprio(1);
    #pragma unroll
    for (int i = 0; i < 4; ++i)
      #pragma unroll
      for (int n = 0; n < NW; ++n)
        acc[MB + i][n] = MFMA16(af[i], bb[n], acc[MB + i][n]);
    __builtin_amdgcn_s_setprio(0);
  };
  auto GATE = [&]() {
    asm volatile("s_waitcnt vmcnt(2)" ::: "memory");
  };

  STAGE_A(0, 0, 0); STAGE_A(0, 1, 0);
  STAGE_B(0, 0);
  STAGE_B(1, 1);
  GATE();
  SBAR;

  for (int J = 0; J < 16; ++J) {
    const int u = 2 * J;
    const bool more = (J < 15);
    LDA(0, 0, 0); LDB(0, 0, b0);
    STAGE_A(1, 0, u + 1);
    SBAR; LGKM0; MM(0, b0); SBAR;
    LDA(0, 0, 4);
    STAGE_A(1, 1, u + 1);
    SBAR; LGKM0; MM(4, b0); SBAR;
    LDA(0, 1, 0); LDB(0, 1, b1);
    SBAR; LGKM0; MM(0, b1); SBAR;
    LDA(0, 1, 4);
    if (more) STAGE_B(0, u + 2);
    SBAR; LGKM0; MM(4, b1);
    if (more) { GATE(); } else { asm volatile("s_waitcnt vmcnt(0)" ::: "memory"); }
    SBAR;
    LDA(1, 0, 0); LDB(1, 0, b0);
    if (more) STAGE_A(0, 0, u + 2);
    SBAR; LGKM0; MM(0, b0); SBAR;
    LDA(1, 0, 4);
    if (more) STAGE_A(0, 1, u + 2);
    SBAR; LGKM0; MM(4, b0); SBAR;
    LDA(1, 1, 0); LDB(1, 1, b1);
    SBAR; LGKM0; MM(0, b1); SBAR;
    LDA(1, 1, 4);
    if (more) STAGE_B(1, u + 3);
    SBAR; LGKM0; MM(4, b1);
    if (more) { GATE(); SBAR; }
  }

  #pragma unroll
  for (int m = 0; m < 8; ++m) {
    const int row0 = brow + wr * 128 + m * 16 + lg * 4;
    #pragma unroll
    for (int n = 0; n < NW; ++n) {
      const int col = bcol + wc * (NW * 16) + n * 16 + lr;
      const float bv = bias[col];
      #pragma unroll
      for (int r = 0; r < 4; ++r)
        Cout[(size_t)(row0 + r) * H + col] = acc[m][n][r] + bv;
    }
  }
}

__global__ __launch_bounds__(512, 2) void gemm_o8(const u16* __restrict__ A,
                                                  const u16* __restrict__ W,
                                                  const float* __restrict__ bias,
                                                  float* __restrict__ C) {
  __shared__ u16 AsL[2 * 256 * 64];   // 64 KiB
  __shared__ u16 BsL[2 * 128 * 64];   // 32 KiB
  const int id = blockIdx.x;
  const int xcd = id & 7, sid = id >> 3;
  const int bx = xcd * 2 + (sid & 1), by = sid >> 1;
  gemm_body<2>(A, W, bias, C, by * 256, bx * 128, AsL, BsL);
}

// ---------------- causal flash attention (unchanged) ----------------
__global__ __launch_bounds__(256) void attn_fwd(const u16* __restrict__ Q,
                                                const u16* __restrict__ Kx,
                                                const u16* __restrict__ Vt,
                                                u16* __restrict__ O) {
  const int id = blockIdx.x;
  const int xcd = id & 7, slot = id >> 3;
  const int bh = (slot >> 4) * 8 + xcd;    // 0..31
  const int pid = slot & 15;               // 0..15
  const int b = bh >> 4, h = bh & 15;
  const int t = threadIdx.x, w = t >> 6, l = t & 63;
  const int lr = l & 15, lg = l >> 4;
  const int swz = lr & 7;

  __shared__ u16 Ks[2][64 * 128];
  __shared__ u16 Vs[2][128 * 64];
  __shared__ u16 P_lds[4][16 * 64];
  u16* pw = &P_lds[w][0];

  const u16* kbase = Kx + (size_t)(b * S) * H + h * HD;
  const u16* vbase = Vt + (size_t)bh * HD * S;

  auto stageK = [&](int bf, int k0) {
    #pragma unroll
    for (int it = 0; it < 4; ++it) {
      int c = it * 256 + t;
      int row = c >> 4, j = c & 15;
      gld16(kbase + (size_t)(k0 + row) * H + ((j ^ (row & 7)) * 8), &Ks[bf][0] + c * 8);
    }
  };
  auto stageV = [&](int bf, int k0) {
    #pragma unroll
    for (int it = 0; it < 4; ++it) {
      int c = it * 256 + t;
      int row = c >> 3, j = c & 7;
      gld16(vbase + (size_t)row * S + k0 + ((j ^ (row & 7)) * 8), &Vs[bf][0] + c * 8);
    }
  };

  int cur = 0;
  for (int qi = 0; qi < 2; ++qi) {
    const int qt = qi ? pid : (31 - pid);
    const int q0 = qt * 64 + w * 16;

    bf16x8 qa[4];
    const u16* qbase = Q + (size_t)(b * S + q0 + lr) * H + h * HD;
    #pragma unroll
    for (int ks = 0; ks < 4; ++ks)
      qa[ks] = *(const bf16x8*)(qbase + ks * 32 + lg * 8);

    f32x4 acc[8] = {};
    float mrun[4], lrun[4];
    #pragma unroll
    for (int r = 0; r < 4; ++r) { mrun[r] = -1e30f; lrun[r] = 0.f; }

    __syncthreads();
    stageK(cur, 0);
    stageV(cur, 0);
    __syncthreads();

    for (int kt = 0; kt <= qt; ++kt) {
      if (kt < qt) {
        stageK(cur ^ 1, (kt + 1) * 64);
        stageV(cur ^ 1, (kt + 1) * 64);
      }
      const u16* kl = &Ks[cur][0];
      const u16* vl = &Vs[cur][0];

      f32x4 sc[4] = {};
      __builtin_amdgcn_s_setprio(1);
      #pragma unroll
      for (int ks = 0; ks < 4; ++ks) {
        #pragma unroll
        for (int f = 0; f < 4; ++f) {
          bf16x8 kf = *(const bf16x8*)(kl + (f * 16 + lr) * 128 + (((ks * 4 + lg) ^ swz) * 8));
          sc[f] = __builtin_amdgcn_mfma_f32_16x16x32_bf16(qa[ks], kf, sc[f], 0, 0, 0);
        }
      }
      __builtin_amdgcn_s_setprio(0);
      const bool diag = (kt == qt);
      float p[4][4];
      #pragma unroll
      for (int f = 0; f < 4; ++f)
        #pragma unroll
        for (int r = 0; r < 4; ++r) {
          float v = sc[f][r];
          if (diag && (f * 16 + lr > w * 16 + lg * 4 + r)) v = -1e30f;
          p[f][r] = v;
        }
      float mx[4];
      #pragma unroll
      for (int r = 0; r < 4; ++r) {
        float m0 = fmaxf(fmaxf(p[0][r], p[1][r]), fmaxf(p[2][r], p[3][r]));
        m0 = fmaxf(m0, __shfl_xor(m0, 1));
        m0 = fmaxf(m0, __shfl_xor(m0, 2));
        m0 = fmaxf(m0, __shfl_xor(m0, 4));
        m0 = fmaxf(m0, __shfl_xor(m0, 8));
        mx[r] = m0;
      }
      bool grow = (mx[0] > mrun[0] + 8.f) || (mx[1] > mrun[1] + 8.f) ||
                  (mx[2] > mrun[2] + 8.f) || (mx[3] > mrun[3] + 8.f);
      if (__any(grow)) {
        float resc[4];
        #pragma unroll
        for (int r = 0; r < 4; ++r) {
          float mnew = fmaxf(mrun[r], mx[r]);
          resc[r] = __expf(mrun[r] - mnew);
          mrun[r] = mnew;
          lrun[r] *= resc[r];
        }
        #pragma unroll
        for (int fd = 0; fd < 8; ++fd) {
          f32x4 a = acc[fd];
          a[0] *= resc[0]; a[1] *= resc[1]; a[2] *= resc[2]; a[3] *= resc[3];
          acc[fd] = a;
        }
      }
      #pragma unroll
      for (int r = 0; r < 4; ++r) {
        float sum = 0.f;
        #pragma unroll
        for (int f = 0; f < 4; ++f) {
          float e = __expf(p[f][r] - mrun[r]);
          p[f][r] = e;
          sum += e;
        }
        sum += __shfl_xor(sum, 1);
        sum += __shfl_xor(sum, 2);
        sum += __shfl_xor(sum, 4);
        sum += __shfl_xor(sum, 8);
        lrun[r] += sum;
      }
      {
        const int r0 = lg * 4;
        #pragma unroll
        for (int f = 0; f < 4; ++f) {
          const int col = f * 16 + lr;
          unsigned w01 = cvt_pk_bf16(p[f][0], p[f][1]);
          unsigned w23 = cvt_pk_bf16(p[f][2], p[f][3]);
          pw[(r0 + 0) * 64 + (col ^ (((r0 + 0) & 7) << 3))] = (u16)(w01 & 0xffffu);
          pw[(r0 + 1) * 64 + (col ^ (((r0 + 1) & 7) << 3))] = (u16)(w01 >> 16);
          pw[(r0 + 2) * 64 + (col ^ (((r0 + 2) & 7) << 3))] = (u16)(w23 & 0xffffu);
          pw[(r0 + 3) * 64 + (col ^ (((r0 + 3) & 7) << 3))] = (u16)(w23 >> 16);
        }
      }
      __builtin_amdgcn_s_setprio(1);
      #pragma unroll
      for (int ks = 0; ks < 2; ++ks) {
        int col0 = ks * 32 + lg * 8;
        bf16x8 pa = *(const bf16x8*)(pw + lr * 64 + (col0 ^ (swz << 3)));
        #pragma unroll
        for (int fd = 0; fd < 8; ++fd) {
          bf16x8 vb = *(const bf16x8*)(vl + (fd * 16 + lr) * 64 + (((ks * 4 + lg) ^ swz) * 8));
          acc[fd] = __builtin_amdgcn_mfma_f32_16x16x32_bf16(pa, vb, acc[fd], 0, 0, 0);
        }
      }
      __builtin_amdgcn_s_setprio(0);
      __syncthreads();
      cur ^= 1;
    }

    u16* ob = O + (size_t)(b * S + q0 + lg * 4) * H + h * HD;
    #pragma unroll
    for (int r = 0; r < 4; ++r) {
      float inv = 1.f / lrun[r];
      #pragma unroll
      for (int fd = 0; fd < 8; ++fd)
        ob[(size_t)r * H + fd * 16 + lr] = f2bf(acc[fd][r] * inv);
    }
  }
}

// ---------------- launch ----------------
extern "C" void kernel_launch(void* const* d_in, const int* in_sizes, int n_in,
                              void* d_out, int out_size, void* d_ws, size_t ws_size,
                              hipStream_t stream) {
  const float* x  = (const float*)d_in[0];
  const float* wq = (const float*)d_in[1];
  const float* bq = (const float*)d_in[2];
  const float* wk = (const float*)d_in[3];
  const float* bk = (const float*)d_in[4];
  const float* wv = (const float*)d_in[5];
  const float* bv = (const float*)d_in[6];
  const float* wo = (const float*)d_in[7];
  const float* bo = (const float*)d_in[8];

  char* ws = (char*)d_ws;
  u16*   xb    = (u16*)(ws);                      // 16 MiB  [M][H] bf16
  u16*   wqkvb = (u16*)(ws + (16ull << 20));      // 24 MiB  [6144][2048] (Wq|Wk|Wv)
  u16*   wob   = (u16*)(ws + (40ull << 20));      //  8 MiB
  u16*   Qb    = (u16*)(ws + (48ull << 20));      // 16 MiB
  u16*   Kb    = (u16*)(ws + (64ull << 20));      // 16 MiB
  u16*   Vt    = (u16*)(ws + (80ull << 20));      // 16 MiB [bh][d][s]
  u16*   Ob    = (u16*)(ws + (96ull << 20));      // 16 MiB
  float* tab   = (float*)(ws + (112ull << 20));   //  1 MiB cos/sin
  float* bqkv  = (float*)(ws + (113ull << 20));   // 24 KiB [6144]

  cast_kernel<<<M * H / 1024, 256, 0, stream>>>(x, xb, M * H);
  cast4_kernel<<<dim3(H * H / 1024, 4), 256, 0, stream>>>(
      wq, wk, wv, wo, wqkvb, wqkvb + (size_t)H * H, wqkvb + 2ull * H * H, wob);
  rope_table_k<<<(S * 64 + 255) / 256, 256, 0, stream>>>(tab);
  concat_bias_k<<<24, 256, 0, stream>>>(bq, bk, bv, bqkv);

  gemm_qkv4<<<384, 512, 0, stream>>>(xb, wqkvb, bqkv, tab, Qb, Kb, Vt);

  attn_fwd<<<512, 256, 0, stream>>>(Qb, Kb, Vt, Ob);

  gemm_o8<<<256, 512, 0, stream>>>(Ob, wob, bo, (float*)d_out);
}

// Round 7
// 293.607 us; speedup vs baseline: 1.0112x; 1.0112x over previous
//
#include <hip/hip_runtime.h>

typedef unsigned short u16;
typedef __attribute__((ext_vector_type(8))) __bf16 bf16x8;
typedef __attribute__((ext_vector_type(4))) float f32x4;
typedef __attribute__((ext_vector_type(4))) u16 u16x4;
typedef __attribute__((ext_vector_type(8))) u16 u16x8;

constexpr int S = 2048;
constexpr int H = 2048;
constexpr int NH = 16;
constexpr int HD = 128;
constexpr int M = 4096;   // B*S
constexpr float SCALE = 0.08838834764831845f;  // 1/sqrt(128)

__device__ __forceinline__ u16 f2bf(float f) {
  union { float f; unsigned u; } v; v.f = f;
  unsigned r = v.u + 0x7fffu + ((v.u >> 16) & 1u);  // RNE
  return (u16)(r >> 16);
}
__device__ __forceinline__ float bf2f(u16 u) {
  union { unsigned u; float f; } v; v.u = ((unsigned)u) << 16;
  return v.f;
}
__device__ __forceinline__ unsigned cvt_pk_bf16(float lo, float hi) {
  unsigned r;
  asm("v_cvt_pk_bf16_f32 %0, %1, %2" : "=v"(r) : "v"(lo), "v"(hi));
  return r;
}
__device__ __forceinline__ f32x4 MFMA16(bf16x8 a, bf16x8 b, f32x4 c) {
  return __builtin_amdgcn_mfma_f32_16x16x32_bf16(a, b, c, 0, 0, 0);
}

// async global->LDS, 16 bytes per lane. LDS dest must be wave-uniform base + lane*16.
__device__ __forceinline__ void gld16(const u16* g, u16* l) {
  __builtin_amdgcn_global_load_lds(
      (const __attribute__((address_space(1))) void*)g,
      (__attribute__((address_space(3))) void*)l, 16, 0, 0);
}

// plain barrier — NO sched_barrier fences (m141: order-pinning costs ~1.7x).
// Compiler emits its own counted lgkmcnt waits before MFMA use (m97 asm evidence).
#define BAR  __builtin_amdgcn_s_barrier()

// ---------------- fp32 -> bf16 cast (x) ----------------
__global__ __launch_bounds__(256) void cast_kernel(const float* __restrict__ in,
                                                   u16* __restrict__ out, int n) {
  int i = (blockIdx.x * 256 + threadIdx.x) * 4;
  if (i >= n) return;
  float4 v = *(const float4*)(in + i);
  u16x4 o;
  o[0] = f2bf(v.x); o[1] = f2bf(v.y); o[2] = f2bf(v.z); o[3] = f2bf(v.w);
  *(u16x4*)(out + i) = o;
}

// ---------------- 4 weight casts in one dispatch ----------------
__global__ __launch_bounds__(256) void cast4_kernel(const float* __restrict__ i0,
                                                    const float* __restrict__ i1,
                                                    const float* __restrict__ i2,
                                                    const float* __restrict__ i3,
                                                    u16* o0, u16* o1, u16* o2, u16* o3) {
  const float* in; u16* out;
  switch (blockIdx.y) {
    case 0: in = i0; out = o0; break;
    case 1: in = i1; out = o1; break;
    case 2: in = i2; out = o2; break;
    default: in = i3; out = o3; break;
  }
  int i = (blockIdx.x * 256 + threadIdx.x) * 4;
  float4 v = *(const float4*)(in + i);
  u16x4 o;
  o[0] = f2bf(v.x); o[1] = f2bf(v.y); o[2] = f2bf(v.z); o[3] = f2bf(v.w);
  *(u16x4*)(out + i) = o;
}

// ---------------- concat biases into [6144] ----------------
__global__ __launch_bounds__(256) void concat_bias_k(const float* __restrict__ bq,
                                                     const float* __restrict__ bk,
                                                     const float* __restrict__ bv,
                                                     float* __restrict__ bqkv) {
  int i = blockIdx.x * 256 + threadIdx.x;  // 0..6143
  const float* src = (i < 2048) ? bq : (i < 4096) ? bk : bv;
  bqkv[i] = src[i & 2047];
}

// ---------------- RoPE cos/sin table ----------------
__global__ __launch_bounds__(256) void rope_table_k(float* __restrict__ tab) {
  int i = blockIdx.x * 256 + threadIdx.x;
  if (i >= S * 64) return;
  int s = i >> 6, d = i & 63;
  float freq = expf(-(float)d * (9.210340371976184f / 64.f));  // 10000^(-d/64)
  float ang = (float)s * freq;
  tab[i * 2]     = cosf(ang);
  tab[i * 2 + 1] = sinf(ang);
}

// ================= fused QKV GEMM: 256x256 tile, NW=4, 8-phase =================
// Identical geometry/ledger to R6; ONLY change: no sched_barrier / explicit lgkmcnt(0).
__global__ __launch_bounds__(512, 2) void gemm_qkv4(const u16* __restrict__ A,
                                                    const u16* __restrict__ Bw,
                                                    const float* __restrict__ bias,
                                                    const float* __restrict__ tab,
                                                    u16* __restrict__ Qb,
                                                    u16* __restrict__ Kb,
                                                    u16* __restrict__ Vt) {
  __shared__ u16 AsL[2 * 256 * 64];   // 64 KiB
  __shared__ u16 BsL[2 * 256 * 64];   // 64 KiB

  const int id = blockIdx.x;
  const int xcd = id & 7, sid = id >> 3;           // sid 0..47
  const int bx = xcd * 3 + (sid % 3);              // 0..23
  const int by = sid / 3;                          // 0..15
  const int brow = by * 256, bcol = bx * 256;
  const int sel = bcol >> 11;                      // 0=Q 1=K 2=V

  const int t = threadIdx.x;
  const int w = t >> 6, l = t & 63;
  const int wr = w >> 2, wc = w & 3;
  const int lr = l & 15, lg = l >> 4;
  const int swz = lr & 7;

  f32x4 acc[8][4] = {};
  bf16x8 af[4], b0[4], b1[4];

  const int sr = t >> 3, sj = t & 7;

  auto STAGE_A = [&](int BUF, int HALF, int TILE) {
    u16* d = AsL + BUF * (256 * 64) + HALF * (128 * 64);
    const u16* sp = A + (size_t)(brow + HALF * 128) * H + TILE * 64;
    gld16(sp + (size_t)sr * H        + ((sj ^ (sr & 7)) * 8), d + t * 8);
    gld16(sp + (size_t)(64 + sr) * H + ((sj ^ (sr & 7)) * 8), d + (512 + t) * 8);
  };
  auto STAGE_B = [&](int BUF, int TILE) {
    u16* d = BsL + BUF * (256 * 64);
    const u16* sp = Bw + (size_t)bcol * H + TILE * 64;
    #pragma unroll
    for (int i = 0; i < 4; ++i)
      gld16(sp + (size_t)(i * 64 + sr) * H + ((sj ^ (sr & 7)) * 8),
            d + (i * 512 + t) * 8);
  };
  auto LDA = [&](int BUF, int KH, int MB) {
    const u16* base = AsL + BUF * (256 * 64) + (wr * 128 + MB * 16 + lr) * 64;
    #pragma unroll
    for (int i = 0; i < 4; ++i)
      af[i] = *(const bf16x8*)(base + i * (16 * 64) + (((KH * 4 + lg) ^ swz) * 8));
  };
  auto LDB = [&](int BUF, int KH, bf16x8* bb) {
    const u16* base = BsL + BUF * (256 * 64) + (wc * 64 + lr) * 64;
    #pragma unroll
    for (int n = 0; n < 4; ++n)
      bb[n] = *(const bf16x8*)(base + n * (16 * 64) + (((KH * 4 + lg) ^ swz) * 8));
  };
  auto MM = [&](int MB, bf16x8* bb) {
    __builtin_amdgcn_s_setprio(1);
    #pragma unroll
    for (int i = 0; i < 4; ++i)
      #pragma unroll
      for (int n = 0; n < 4; ++n)
        acc[MB + i][n] = MFMA16(af[i], bb[n], acc[MB + i][n]);
    __builtin_amdgcn_s_setprio(0);
  };

  // prologue: A0<-t0 (4), B0<-t0 (4), B1<-t1 (4); retire all but B1
  STAGE_A(0, 0, 0); STAGE_A(0, 1, 0);
  STAGE_B(0, 0);
  STAGE_B(1, 1);
  asm volatile("s_waitcnt vmcnt(4)" ::: "memory");
  BAR;

  for (int J = 0; J < 16; ++J) {
    const int u = 2 * J;
    const bool more = (J < 15);
    // ---- tile u (buf0) ----
    LDA(0, 0, 0); LDB(0, 0, b0);
    STAGE_A(1, 0, u + 1);
    BAR; MM(0, b0); BAR;

    LDA(0, 0, 4);
    STAGE_A(1, 1, u + 1);
    BAR; MM(4, b0); BAR;

    LDA(0, 1, 0); LDB(0, 1, b1);
    BAR; MM(0, b1); BAR;

    LDA(0, 1, 4);
    if (more) STAGE_B(0, u + 2);
    BAR; MM(4, b1);
    if (more) { asm volatile("s_waitcnt vmcnt(4)" ::: "memory"); }
    else      { asm volatile("s_waitcnt vmcnt(0)" ::: "memory"); }
    BAR;
    // ---- tile u+1 (buf1) ----
    LDA(1, 0, 0); LDB(1, 0, b0);
    if (more) STAGE_A(0, 0, u + 2);
    BAR; MM(0, b0); BAR;

    LDA(1, 0, 4);
    if (more) STAGE_A(0, 1, u + 2);
    BAR; MM(4, b0); BAR;

    LDA(1, 1, 0); LDB(1, 1, b1);
    BAR; MM(0, b1); BAR;

    LDA(1, 1, 4);
    if (more) STAGE_B(1, u + 3);
    BAR; MM(4, b1);
    if (more) { asm volatile("s_waitcnt vmcnt(4)" ::: "memory"); BAR; }
  }

  // ================= epilogue =================
  if (sel < 2) {
    // Q/K: bias + RoPE + bf16. Pair-exchange (col ^ 64 <-> wave wc^1) via LDS.
    float* lf = (float*)AsL;            // 8 * 16*66 * 4B = 33 KiB
    u16* Cq = sel ? Kb : Qb;
    const float scl = sel ? 1.f : SCALE;
    #pragma unroll
    for (int m = 0; m < 8; ++m) {
      __syncthreads();
      float mine[4][4];
      #pragma unroll
      for (int n = 0; n < 4; ++n) {
        const float bv = bias[bcol + wc * 64 + n * 16 + lr];
        #pragma unroll
        for (int r = 0; r < 4; ++r) {
          mine[n][r] = acc[m][n][r] + bv;
          lf[w * (16 * 66) + (lg * 4 + r) * 66 + n * 16 + lr] = mine[n][r];
        }
      }
      __syncthreads();
      #pragma unroll
      for (int n = 0; n < 4; ++n) {
        const int j = n * 16 + lr;
        const int hcol = ((bcol & 2047) + wc * 64 + j);
        #pragma unroll
        for (int r = 0; r < 4; ++r) {
          const int row = brow + wr * 128 + m * 16 + lg * 4 + r;
          const int s = row & (S - 1);
          float pr = lf[(w ^ 1) * (16 * 66) + (lg * 4 + r) * 66 + j];
          float2 cs = ((const float2*)tab)[s * 64 + j];
          float out = (wc & 1) ? (mine[n][r] * cs.x + pr * cs.y)
                               : (mine[n][r] * cs.x - pr * cs.y);
          Cq[(size_t)row * H + hcol] = f2bf(out * scl);
        }
      }
    }
  } else {
    // V: bias + transposed store Vt[((b*16+h)*128+d)*S + s]
    #pragma unroll
    for (int m = 0; m < 8; ++m) {
      const int row0 = brow + wr * 128 + m * 16 + lg * 4;
      #pragma unroll
      for (int n = 0; n < 4; ++n) {
        const int col = (bcol & 2047) + wc * 64 + n * 16 + lr;
        const float bv = bias[bcol + wc * 64 + n * 16 + lr];
        const int hh = col >> 7, d = col & 127;
        const int b = row0 >> 11, s0 = row0 & (S - 1);
        u16x4 pk;
        #pragma unroll
        for (int r = 0; r < 4; ++r) pk[r] = f2bf(acc[m][n][r] + bv);
        *(u16x4*)(Vt + ((size_t)((b * 16 + hh) * 128 + d)) * S + s0) = pk;
      }
    }
  }
}

// ================= out-proj GEMM (256x128, NW=2) — fences removed =================
template<int NW>
__device__ __forceinline__ void gemm_body(const u16* __restrict__ A,
                                          const u16* __restrict__ Bw,
                                          const float* __restrict__ bias,
                                          float* __restrict__ Cout,
                                          int brow, int bcol,
                                          u16* AsL, u16* BsL) {
  const int t = threadIdx.x;
  const int w = t >> 6, l = t & 63;
  const int wr = w >> 2, wc = w & 3;
  const int lr = l & 15, lg = l >> 4;
  const int swz = lr & 7;

  f32x4 acc[8][NW] = {};
  bf16x8 af[4], b0[NW], b1[NW];

  const int sr = t >> 3, sj = t & 7;

  auto STAGE_A = [&](int BUF, int HALF, int TILE) {
    u16* d = AsL + BUF * (256 * 64) + HALF * (128 * 64);
    const u16* sp = A + (size_t)(brow + HALF * 128) * H + TILE * 64;
    gld16(sp + (size_t)sr * H        + ((sj ^ (sr & 7)) * 8), d + t * 8);
    gld16(sp + (size_t)(64 + sr) * H + ((sj ^ (sr & 7)) * 8), d + (512 + t) * 8);
  };
  auto STAGE_B = [&](int BUF, int TILE) {
    u16* d = BsL + BUF * (NW * 64 * 64);
    const u16* sp = Bw + (size_t)bcol * H + TILE * 64;
    #pragma unroll
    for (int i = 0; i < NW; ++i)
      gld16(sp + (size_t)(i * 64 + sr) * H + ((sj ^ (sr & 7)) * 8),
            d + (i * 512 + t) * 8);
  };
  auto LDA = [&](int BUF, int KH, int MB) {
    const u16* base = AsL + BUF * (256 * 64) + (wr * 128 + MB * 16 + lr) * 64;
    #pragma unroll
    for (int i = 0; i < 4; ++i)
      af[i] = *(const bf16x8*)(base + i * (16 * 64) + (((KH * 4 + lg) ^ swz) * 8));
  };
  auto LDB = [&](int BUF, int KH, bf16x8* bb) {
    const u16* base = BsL + BUF * (NW * 64 * 64) + (wc * (NW * 16) + lr) * 64;
    #pragma unroll
    for (int n = 0; n < NW; ++n)
      bb[n] = *(const bf16x8*)(base + n * (16 * 64) + (((KH * 4 + lg) ^ swz) * 8));
  };
  auto MM = [&](int MB, bf16x8* bb) {
    __builtin_amdgcn_s_setprio(1);
    #pragma unroll
    for (int i = 0; i < 4; ++i)
      #pragma unroll
      for (int n = 0; n < NW; ++n)
        acc[MB + i][n] = MFMA16(af[i], bb[n], acc[MB + i][n]);
    __builtin_amdgcn_s_setprio(0);
  };

  STAGE_A(0, 0, 0); STAGE_A(0, 1, 0);
  STAGE_B(0, 0);
  STAGE_B(1, 1);
  asm volatile("s_waitcnt vmcnt(2)" ::: "memory");
  BAR;

  for (int J = 0; J < 16; ++J) {
    const int u = 2 * J;
    const bool more = (J < 15);
    LDA(0, 0, 0); LDB(0, 0, b0);
    STAGE_A(1, 0, u + 1);
    BAR; MM(0, b0); BAR;
    LDA(0, 0, 4);
    STAGE_A(1, 1, u + 1);
    BAR; MM(4, b0); BAR;
    LDA(0, 1, 0); LDB(0, 1, b1);
    BAR; MM(0, b1); BAR;
    LDA(0, 1, 4);
    if (more) STAGE_B(0, u + 2);
    BAR; MM(4, b1);
    if (more) { asm volatile("s_waitcnt vmcnt(2)" ::: "memory"); }
    else      { asm volatile("s_waitcnt vmcnt(0)" ::: "memory"); }
    BAR;
    LDA(1, 0, 0); LDB(1, 0, b0);
    if (more) STAGE_A(0, 0, u + 2);
    BAR; MM(0, b0); BAR;
    LDA(1, 0, 4);
    if (more) STAGE_A(0, 1, u + 2);
    BAR; MM(4, b0); BAR;
    LDA(1, 1, 0); LDB(1, 1, b1);
    BAR; MM(0, b1); BAR;
    LDA(1, 1, 4);
    if (more) STAGE_B(1, u + 3);
    BAR; MM(4, b1);
    if (more) { asm volatile("s_waitcnt vmcnt(2)" ::: "memory"); BAR; }
  }

  #pragma unroll
  for (int m = 0; m < 8; ++m) {
    const int row0 = brow + wr * 128 + m * 16 + lg * 4;
    #pragma unroll
    for (int n = 0; n < NW; ++n) {
      const int col = bcol + wc * (NW * 16) + n * 16 + lr;
      const float bv = bias[col];
      #pragma unroll
      for (int r = 0; r < 4; ++r)
        Cout[(size_t)(row0 + r) * H + col] = acc[m][n][r] + bv;
    }
  }
}

__global__ __launch_bounds__(512, 2) void gemm_o8(const u16* __restrict__ A,
                                                  const u16* __restrict__ W,
                                                  const float* __restrict__ bias,
                                                  float* __restrict__ C) {
  __shared__ u16 AsL[2 * 256 * 64];   // 64 KiB
  __shared__ u16 BsL[2 * 128 * 64];   // 32 KiB
  const int id = blockIdx.x;
  const int xcd = id & 7, sid = id >> 3;
  const int bx = xcd * 2 + (sid & 1), by = sid >> 1;
  gemm_body<2>(A, W, bias, C, by * 256, bx * 128, AsL, BsL);
}

// ---------------- causal flash attention (unchanged) ----------------
__global__ __launch_bounds__(256) void attn_fwd(const u16* __restrict__ Q,
                                                const u16* __restrict__ Kx,
                                                const u16* __restrict__ Vt,
                                                u16* __restrict__ O) {
  const int id = blockIdx.x;
  const int xcd = id & 7, slot = id >> 3;
  const int bh = (slot >> 4) * 8 + xcd;    // 0..31
  const int pid = slot & 15;               // 0..15
  const int b = bh >> 4, h = bh & 15;
  const int t = threadIdx.x, w = t >> 6, l = t & 63;
  const int lr = l & 15, lg = l >> 4;
  const int swz = lr & 7;

  __shared__ u16 Ks[2][64 * 128];
  __shared__ u16 Vs[2][128 * 64];
  __shared__ u16 P_lds[4][16 * 64];
  u16* pw = &P_lds[w][0];

  const u16* kbase = Kx + (size_t)(b * S) * H + h * HD;
  const u16* vbase = Vt + (size_t)bh * HD * S;

  auto stageK = [&](int bf, int k0) {
    #pragma unroll
    for (int it = 0; it < 4; ++it) {
      int c = it * 256 + t;
      int row = c >> 4, j = c & 15;
      gld16(kbase + (size_t)(k0 + row) * H + ((j ^ (row & 7)) * 8), &Ks[bf][0] + c * 8);
    }
  };
  auto stageV = [&](int bf, int k0) {
    #pragma unroll
    for (int it = 0; it < 4; ++it) {
      int c = it * 256 + t;
      int row = c >> 3, j = c & 7;
      gld16(vbase + (size_t)row * S + k0 + ((j ^ (row & 7)) * 8), &Vs[bf][0] + c * 8);
    }
  };

  int cur = 0;
  for (int qi = 0; qi < 2; ++qi) {
    const int qt = qi ? pid : (31 - pid);
    const int q0 = qt * 64 + w * 16;

    bf16x8 qa[4];
    const u16* qbase = Q + (size_t)(b * S + q0 + lr) * H + h * HD;
    #pragma unroll
    for (int ks = 0; ks < 4; ++ks)
      qa[ks] = *(const bf16x8*)(qbase + ks * 32 + lg * 8);

    f32x4 acc[8] = {};
    float mrun[4], lrun[4];
    #pragma unroll
    for (int r = 0; r < 4; ++r) { mrun[r] = -1e30f; lrun[r] = 0.f; }

    __syncthreads();
    stageK(cur, 0);
    stageV(cur, 0);
    __syncthreads();

    for (int kt = 0; kt <= qt; ++kt) {
      if (kt < qt) {
        stageK(cur ^ 1, (kt + 1) * 64);
        stageV(cur ^ 1, (kt + 1) * 64);
      }
      const u16* kl = &Ks[cur][0];
      const u16* vl = &Vs[cur][0];

      f32x4 sc[4] = {};
      __builtin_amdgcn_s_setprio(1);
      #pragma unroll
      for (int ks = 0; ks < 4; ++ks) {
        #pragma unroll
        for (int f = 0; f < 4; ++f) {
          bf16x8 kf = *(const bf16x8*)(kl + (f * 16 + lr) * 128 + (((ks * 4 + lg) ^ swz) * 8));
          sc[f] = __builtin_amdgcn_mfma_f32_16x16x32_bf16(qa[ks], kf, sc[f], 0, 0, 0);
        }
      }
      __builtin_amdgcn_s_setprio(0);
      const bool diag = (kt == qt);
      float p[4][4];
      #pragma unroll
      for (int f = 0; f < 4; ++f)
        #pragma unroll
        for (int r = 0; r < 4; ++r) {
          float v = sc[f][r];
          if (diag && (f * 16 + lr > w * 16 + lg * 4 + r)) v = -1e30f;
          p[f][r] = v;
        }
      float mx[4];
      #pragma unroll
      for (int r = 0; r < 4; ++r) {
        float m0 = fmaxf(fmaxf(p[0][r], p[1][r]), fmaxf(p[2][r], p[3][r]));
        m0 = fmaxf(m0, __shfl_xor(m0, 1));
        m0 = fmaxf(m0, __shfl_xor(m0, 2));
        m0 = fmaxf(m0, __shfl_xor(m0, 4));
        m0 = fmaxf(m0, __shfl_xor(m0, 8));
        mx[r] = m0;
      }
      bool grow = (mx[0] > mrun[0] + 8.f) || (mx[1] > mrun[1] + 8.f) ||
                  (mx[2] > mrun[2] + 8.f) || (mx[3] > mrun[3] + 8.f);
      if (__any(grow)) {
        float resc[4];
        #pragma unroll
        for (int r = 0; r < 4; ++r) {
          float mnew = fmaxf(mrun[r], mx[r]);
          resc[r] = __expf(mrun[r] - mnew);
          mrun[r] = mnew;
          lrun[r] *= resc[r];
        }
        #pragma unroll
        for (int fd = 0; fd < 8; ++fd) {
          f32x4 a = acc[fd];
          a[0] *= resc[0]; a[1] *= resc[1]; a[2] *= resc[2]; a[3] *= resc[3];
          acc[fd] = a;
        }
      }
      #pragma unroll
      for (int r = 0; r < 4; ++r) {
        float sum = 0.f;
        #pragma unroll
        for (int f = 0; f < 4; ++f) {
          float e = __expf(p[f][r] - mrun[r]);
          p[f][r] = e;
          sum += e;
        }
        sum += __shfl_xor(sum, 1);
        sum += __shfl_xor(sum, 2);
        sum += __shfl_xor(sum, 4);
        sum += __shfl_xor(sum, 8);
        lrun[r] += sum;
      }
      {
        const int r0 = lg * 4;
        #pragma unroll
        for (int f = 0; f < 4; ++f) {
          const int col = f * 16 + lr;
          unsigned w01 = cvt_pk_bf16(p[f][0], p[f][1]);
          unsigned w23 = cvt_pk_bf16(p[f][2], p[f][3]);
          pw[(r0 + 0) * 64 + (col ^ (((r0 + 0) & 7) << 3))] = (u16)(w01 & 0xffffu);
          pw[(r0 + 1) * 64 + (col ^ (((r0 + 1) & 7) << 3))] = (u16)(w01 >> 16);
          pw[(r0 + 2) * 64 + (col ^ (((r0 + 2) & 7) << 3))] = (u16)(w23 & 0xffffu);
          pw[(r0 + 3) * 64 + (col ^ (((r0 + 3) & 7) << 3))] = (u16)(w23 >> 16);
        }
      }
      __builtin_amdgcn_s_setprio(1);
      #pragma unroll
      for (int ks = 0; ks < 2; ++ks) {
        int col0 = ks * 32 + lg * 8;
        bf16x8 pa = *(const bf16x8*)(pw + lr * 64 + (col0 ^ (swz << 3)));
        #pragma unroll
        for (int fd = 0; fd < 8; ++fd) {
          bf16x8 vb = *(const bf16x8*)(vl + (fd * 16 + lr) * 64 + (((ks * 4 + lg) ^ swz) * 8));
          acc[fd] = __builtin_amdgcn_mfma_f32_16x16x32_bf16(pa, vb, acc[fd], 0, 0, 0);
        }
      }
      __builtin_amdgcn_s_setprio(0);
      __syncthreads();
      cur ^= 1;
    }

    u16* ob = O + (size_t)(b * S + q0 + lg * 4) * H + h * HD;
    #pragma unroll
    for (int r = 0; r < 4; ++r) {
      float inv = 1.f / lrun[r];
      #pragma unroll
      for (int fd = 0; fd < 8; ++fd)
        ob[(size_t)r * H + fd * 16 + lr] = f2bf(acc[fd][r] * inv);
    }
  }
}

// ---------------- launch ----------------
extern "C" void kernel_launch(void* const* d_in, const int* in_sizes, int n_in,
                              void* d_out, int out_size, void* d_ws, size_t ws_size,
                              hipStream_t stream) {
  const float* x  = (const float*)d_in[0];
  const float* wq = (const float*)d_in[1];
  const float* bq = (const float*)d_in[2];
  const float* wk = (const float*)d_in[3];
  const float* bk = (const float*)d_in[4];
  const float* wv = (const float*)d_in[5];
  const float* bv = (const float*)d_in[6];
  const float* wo = (const float*)d_in[7];
  const float* bo = (const float*)d_in[8];

  char* ws = (char*)d_ws;
  u16*   xb    = (u16*)(ws);                      // 16 MiB  [M][H] bf16
  u16*   wqkvb = (u16*)(ws + (16ull << 20));      // 24 MiB  [6144][2048] (Wq|Wk|Wv)
  u16*   wob   = (u16*)(ws + (40ull << 20));      //  8 MiB
  u16*   Qb    = (u16*)(ws + (48ull << 20));      // 16 MiB
  u16*   Kb    = (u16*)(ws + (64ull << 20));      // 16 MiB
  u16*   Vt    = (u16*)(ws + (80ull << 20));      // 16 MiB [bh][d][s]
  u16*   Ob    = (u16*)(ws + (96ull << 20));      // 16 MiB
  float* tab   = (float*)(ws + (112ull << 20));   //  1 MiB cos/sin
  float* bqkv  = (float*)(ws + (113ull << 20));   // 24 KiB [6144]

  cast_kernel<<<M * H / 1024, 256, 0, stream>>>(x, xb, M * H);
  cast4_kernel<<<dim3(H * H / 1024, 4), 256, 0, stream>>>(
      wq, wk, wv, wo, wqkvb, wqkvb + (size_t)H * H, wqkvb + 2ull * H * H, wob);
  rope_table_k<<<(S * 64 + 255) / 256, 256, 0, stream>>>(tab);
  concat_bias_k<<<24, 256, 0, stream>>>(bq, bk, bv, bqkv);

  gemm_qkv4<<<384, 512, 0, stream>>>(xb, wqkvb, bqkv, tab, Qb, Kb, Vt);

  attn_fwd<<<512, 256, 0, stream>>>(Qb, Kb, Vt, Ob);

  gemm_o8<<<256, 512, 0, stream>>>(Ob, wob, bo, (float*)d_out);
}

// Round 8
// 279.975 us; speedup vs baseline: 1.0604x; 1.0487x over previous
//
#include <hip/hip_runtime.h>

typedef unsigned short u16;
typedef __attribute__((ext_vector_type(8))) __bf16 bf16x8;
typedef __attribute__((ext_vector_type(4))) float f32x4;
typedef __attribute__((ext_vector_type(4))) u16 u16x4;
typedef __attribute__((ext_vector_type(8))) u16 u16x8;

constexpr int S = 2048;
constexpr int H = 2048;
constexpr int NH = 16;
constexpr int HD = 128;
constexpr int M = 4096;   // B*S
constexpr float SCALE = 0.08838834764831845f;  // 1/sqrt(128)

__device__ __forceinline__ u16 f2bf(float f) {
  union { float f; unsigned u; } v; v.f = f;
  unsigned r = v.u + 0x7fffu + ((v.u >> 16) & 1u);  // RNE
  return (u16)(r >> 16);
}
__device__ __forceinline__ float bf2f(u16 u) {
  union { unsigned u; float f; } v; v.u = ((unsigned)u) << 16;
  return v.f;
}
__device__ __forceinline__ unsigned cvt_pk_bf16(float lo, float hi) {
  unsigned r;
  asm("v_cvt_pk_bf16_f32 %0, %1, %2" : "=v"(r) : "v"(lo), "v"(hi));
  return r;
}
__device__ __forceinline__ f32x4 MFMA16(bf16x8 a, bf16x8 b, f32x4 c) {
  return __builtin_amdgcn_mfma_f32_16x16x32_bf16(a, b, c, 0, 0, 0);
}

// async global->LDS, 16 bytes per lane. LDS dest must be wave-uniform base + lane*16.
__device__ __forceinline__ void gld16(const u16* g, u16* l) {
  __builtin_amdgcn_global_load_lds(
      (const __attribute__((address_space(1))) void*)g,
      (__attribute__((address_space(3))) void*)l, 16, 0, 0);
}

#define BAR  __builtin_amdgcn_s_barrier()

// ---------------- fp32 -> bf16 cast (x) ----------------
__global__ __launch_bounds__(256) void cast_kernel(const float* __restrict__ in,
                                                   u16* __restrict__ out, int n) {
  int i = (blockIdx.x * 256 + threadIdx.x) * 4;
  if (i >= n) return;
  float4 v = *(const float4*)(in + i);
  u16x4 o;
  o[0] = f2bf(v.x); o[1] = f2bf(v.y); o[2] = f2bf(v.z); o[3] = f2bf(v.w);
  *(u16x4*)(out + i) = o;
}

// ---------------- 4 weight casts in one dispatch ----------------
__global__ __launch_bounds__(256) void cast4_kernel(const float* __restrict__ i0,
                                                    const float* __restrict__ i1,
                                                    const float* __restrict__ i2,
                                                    const float* __restrict__ i3,
                                                    u16* o0, u16* o1, u16* o2, u16* o3) {
  const float* in; u16* out;
  switch (blockIdx.y) {
    case 0: in = i0; out = o0; break;
    case 1: in = i1; out = o1; break;
    case 2: in = i2; out = o2; break;
    default: in = i3; out = o3; break;
  }
  int i = (blockIdx.x * 256 + threadIdx.x) * 4;
  float4 v = *(const float4*)(in + i);
  u16x4 o;
  o[0] = f2bf(v.x); o[1] = f2bf(v.y); o[2] = f2bf(v.z); o[3] = f2bf(v.w);
  *(u16x4*)(out + i) = o;
}

// ---------------- concat biases into [6144] ----------------
__global__ __launch_bounds__(256) void concat_bias_k(const float* __restrict__ bq,
                                                     const float* __restrict__ bk,
                                                     const float* __restrict__ bv,
                                                     float* __restrict__ bqkv) {
  int i = blockIdx.x * 256 + threadIdx.x;  // 0..6143
  const float* src = (i < 2048) ? bq : (i < 4096) ? bk : bv;
  bqkv[i] = src[i & 2047];
}

// ---------------- RoPE cos/sin table ----------------
__global__ __launch_bounds__(256) void rope_table_k(float* __restrict__ tab) {
  int i = blockIdx.x * 256 + threadIdx.x;
  if (i >= S * 64) return;
  int s = i >> 6, d = i & 63;
  float freq = expf(-(float)d * (9.210340371976184f / 64.f));  // 10000^(-d/64)
  float ang = (float)s * freq;
  tab[i * 2]     = cosf(ang);
  tab[i * 2 + 1] = sinf(ang);
}

// ================= 128x128 GEMM, BK=64, 256 thr, 2 blocks/CU (T3-minimum 2-phase) =================
// C[m,n] = sum_k A[m,k]*W[n,k] + bias[n]; K=2048 -> 32 K-tiles, ONE barrier per tile.
// Loop: STAGE(next tile, 8 gld16) -> LDA/LDB/MM (kh0,kh1, compiler-scheduled) -> vmcnt(0) -> BAR.
// Stalls hidden by the co-resident second block (m114 wave-level overlap).
// Chunk-XOR swizzle (source-swizzled stage, same involution on read) -> conflict-free ds_read_b128.
// EMODE 0: fp32 out. EMODE 3: fused QKV epilogue (Q/K: bias+RoPE; V: bias+transpose).
template<int EMODE>
__device__ __forceinline__ void gemm128(const u16* __restrict__ A,
                                        const u16* __restrict__ Bw,
                                        const float* __restrict__ bias,
                                        const float* __restrict__ tab,
                                        void* __restrict__ out0, void* __restrict__ out1,
                                        void* __restrict__ out2,
                                        int brow, int bcol,
                                        u16* AsL, u16* BsL) {
  const int t = threadIdx.x;           // 0..255
  const int w = t >> 6, l = t & 63;
  const int wr = w >> 1, wc = w & 1;
  const int lr = l & 15, lg = l >> 4;
  const int swz = lr & 7;

  f32x4 acc[4][4] = {};

  const int sr = t >> 3, sj = t & 7;   // stage: 32 rows / 8 chunks per gld16 inst

  auto STAGE = [&](int BUF, int TILE) {
    u16* da = AsL + BUF * (128 * 64);
    const u16* sa = A + (size_t)brow * H + TILE * 64;
    #pragma unroll
    for (int it = 0; it < 4; ++it) {
      int row = it * 32 + sr;
      gld16(sa + (size_t)row * H + ((sj ^ (row & 7)) * 8), da + (it * 256 + t) * 8);
    }
    u16* db = BsL + BUF * (128 * 64);
    const u16* sb = Bw + (size_t)bcol * H + TILE * 64;
    #pragma unroll
    for (int it = 0; it < 4; ++it) {
      int row = it * 32 + sr;
      gld16(sb + (size_t)row * H + ((sj ^ (row & 7)) * 8), db + (it * 256 + t) * 8);
    }
  };
  auto LDA = [&](int BUF, int KH, bf16x8* aa) {
    const u16* base = AsL + BUF * (128 * 64) + (wr * 64 + lr) * 64;
    #pragma unroll
    for (int i = 0; i < 4; ++i)
      aa[i] = *(const bf16x8*)(base + i * (16 * 64) + (((KH * 4 + lg) ^ swz) * 8));
  };
  auto LDB = [&](int BUF, int KH, bf16x8* bb) {
    const u16* base = BsL + BUF * (128 * 64) + (wc * 64 + lr) * 64;
    #pragma unroll
    for (int n = 0; n < 4; ++n)
      bb[n] = *(const bf16x8*)(base + n * (16 * 64) + (((KH * 4 + lg) ^ swz) * 8));
  };
  auto MM = [&](bf16x8* aa, bf16x8* bb) {
    __builtin_amdgcn_s_setprio(1);
    #pragma unroll
    for (int i = 0; i < 4; ++i)
      #pragma unroll
      for (int n = 0; n < 4; ++n)
        acc[i][n] = MFMA16(aa[i], bb[n], acc[i][n]);
    __builtin_amdgcn_s_setprio(0);
  };

  // prologue: tile 0 staged, fully visible
  STAGE(0, 0);
  asm volatile("s_waitcnt vmcnt(0)" ::: "memory");
  BAR;

  int c = 0;
  for (int u = 0; u < 32; ++u) {
    if (u < 31) STAGE(c ^ 1, u + 1);   // issue next-tile loads FIRST
    bf16x8 aa[4], bb[4];
    LDA(c, 0, aa); LDB(c, 0, bb); MM(aa, bb);
    LDA(c, 1, aa); LDB(c, 1, bb); MM(aa, bb);
    asm volatile("s_waitcnt vmcnt(0)" ::: "memory");
    BAR;                                // next tile in LDS; this buffer free
    c ^= 1;
  }

  // ================= epilogue =================
  if constexpr (EMODE == 0) {
    float* C = (float*)out0;
    #pragma unroll
    for (int m = 0; m < 4; ++m) {
      const int row0 = brow + wr * 64 + m * 16 + lg * 4;
      #pragma unroll
      for (int n = 0; n < 4; ++n) {
        const int col = bcol + wc * 64 + n * 16 + lr;
        const float bv = bias[col];
        #pragma unroll
        for (int r = 0; r < 4; ++r)
          C[(size_t)(row0 + r) * H + col] = acc[m][n][r] + bv;
      }
    }
  } else {
    const int sel = bcol >> 11;          // 0=Q 1=K 2=V (128-tile never crosses)
    if (sel < 2) {
      // Q/K: bias + RoPE + bf16. Pair-exchange (d ^ 64 <-> wave w^1) via LDS.
      float* lf = (float*)AsL;           // 4 waves * 16*66 * 4B = 16.9 KiB
      u16* Cq = sel ? (u16*)out1 : (u16*)out0;
      const float scl = sel ? 1.f : SCALE;
      #pragma unroll
      for (int m = 0; m < 4; ++m) {
        __syncthreads();
        float mine[4][4];
        #pragma unroll
        for (int n = 0; n < 4; ++n) {
          const float bv = bias[bcol + wc * 64 + n * 16 + lr];
          #pragma unroll
          for (int r = 0; r < 4; ++r) {
            mine[n][r] = acc[m][n][r] + bv;
            lf[w * (16 * 66) + (lg * 4 + r) * 66 + n * 16 + lr] = mine[n][r];
          }
        }
        __syncthreads();
        #pragma unroll
        for (int n = 0; n < 4; ++n) {
          const int j = n * 16 + lr;                 // d & 63
          const int hcol = (bcol & 2047) + wc * 64 + j;
          #pragma unroll
          for (int r = 0; r < 4; ++r) {
            const int row = brow + wr * 64 + m * 16 + lg * 4 + r;
            const int s = row & (S - 1);
            float pr = lf[(w ^ 1) * (16 * 66) + (lg * 4 + r) * 66 + j];
            float2 cs = ((const float2*)tab)[s * 64 + j];
            float out = wc ? (mine[n][r] * cs.x + pr * cs.y)
                           : (mine[n][r] * cs.x - pr * cs.y);
            Cq[(size_t)row * H + hcol] = f2bf(out * scl);
          }
        }
      }
    } else {
      // V: bias + transposed store Vt[((b*16+h)*128+d)*S + s]
      u16* Vt = (u16*)out2;
      #pragma unroll
      for (int m = 0; m < 4; ++m) {
        const int row0 = brow + wr * 64 + m * 16 + lg * 4;
        #pragma unroll
        for (int n = 0; n < 4; ++n) {
          const int col = (bcol & 2047) + wc * 64 + n * 16 + lr;
          const float bv = bias[bcol + wc * 64 + n * 16 + lr];
          const int hh = col >> 7, d = col & 127;
          const int b = row0 >> 11, s0 = row0 & (S - 1);
          u16x4 pk;
          #pragma unroll
          for (int r = 0; r < 4; ++r) pk[r] = f2bf(acc[m][n][r] + bv);
          *(u16x4*)(Vt + ((size_t)((b * 16 + hh) * 128 + d)) * S + s0) = pk;
        }
      }
    }
  }
}

// fused QKV: M=4096 x N=6144, 128x128 tiles -> 32x48 = 1536 blocks (3 exact rounds @2/CU).
// XCD stripe: each XCD owns 6 N-tiles (768 cols, B-stripe 3 MB -> L2-resident).
__global__ __launch_bounds__(256, 2) void gemm_qkv2(const u16* __restrict__ xb,
                                                    const u16* __restrict__ wqkv,
                                                    const float* __restrict__ bqkv,
                                                    const float* __restrict__ tab,
                                                    u16* Qb, u16* Kb, u16* Vt) {
  __shared__ u16 AsL[2 * 128 * 64];   // 32 KiB
  __shared__ u16 BsL[2 * 128 * 64];   // 32 KiB
  const int id = blockIdx.x;
  const int xcd = id & 7, sid = id >> 3;        // sid 0..191
  const int bx = xcd * 6 + (sid % 6);           // 0..47
  const int by = sid / 6;                       // 0..31
  gemm128<3>(xb, wqkv, bqkv, tab, Qb, Kb, Vt, by * 128, bx * 128, AsL, BsL);
}

// out-proj: M=4096 x N=2048 -> 32x16 = 512 blocks (1 exact round @2/CU).
__global__ __launch_bounds__(256, 2) void gemm_o2(const u16* __restrict__ A,
                                                  const u16* __restrict__ W,
                                                  const float* __restrict__ bias,
                                                  float* __restrict__ C) {
  __shared__ u16 AsL[2 * 128 * 64];   // 32 KiB
  __shared__ u16 BsL[2 * 128 * 64];   // 32 KiB
  const int id = blockIdx.x;
  const int xcd = id & 7, sid = id >> 3;        // sid 0..63
  const int bx = xcd * 2 + (sid & 1);           // 0..15
  const int by = sid >> 1;                      // 0..31
  gemm128<0>(A, W, bias, nullptr, C, nullptr, nullptr, by * 128, bx * 128, AsL, BsL);
}

// ---------------- causal flash attention (unchanged) ----------------
__global__ __launch_bounds__(256) void attn_fwd(const u16* __restrict__ Q,
                                                const u16* __restrict__ Kx,
                                                const u16* __restrict__ Vt,
                                                u16* __restrict__ O) {
  const int id = blockIdx.x;
  const int xcd = id & 7, slot = id >> 3;
  const int bh = (slot >> 4) * 8 + xcd;    // 0..31
  const int pid = slot & 15;               // 0..15
  const int b = bh >> 4, h = bh & 15;
  const int t = threadIdx.x, w = t >> 6, l = t & 63;
  const int lr = l & 15, lg = l >> 4;
  const int swz = lr & 7;

  __shared__ u16 Ks[2][64 * 128];
  __shared__ u16 Vs[2][128 * 64];
  __shared__ u16 P_lds[4][16 * 64];
  u16* pw = &P_lds[w][0];

  const u16* kbase = Kx + (size_t)(b * S) * H + h * HD;
  const u16* vbase = Vt + (size_t)bh * HD * S;

  auto stageK = [&](int bf, int k0) {
    #pragma unroll
    for (int it = 0; it < 4; ++it) {
      int c = it * 256 + t;
      int row = c >> 4, j = c & 15;
      gld16(kbase + (size_t)(k0 + row) * H + ((j ^ (row & 7)) * 8), &Ks[bf][0] + c * 8);
    }
  };
  auto stageV = [&](int bf, int k0) {
    #pragma unroll
    for (int it = 0; it < 4; ++it) {
      int c = it * 256 + t;
      int row = c >> 3, j = c & 7;
      gld16(vbase + (size_t)row * S + k0 + ((j ^ (row & 7)) * 8), &Vs[bf][0] + c * 8);
    }
  };

  int cur = 0;
  for (int qi = 0; qi < 2; ++qi) {
    const int qt = qi ? pid : (31 - pid);
    const int q0 = qt * 64 + w * 16;

    bf16x8 qa[4];
    const u16* qbase = Q + (size_t)(b * S + q0 + lr) * H + h * HD;
    #pragma unroll
    for (int ks = 0; ks < 4; ++ks)
      qa[ks] = *(const bf16x8*)(qbase + ks * 32 + lg * 8);

    f32x4 acc[8] = {};
    float mrun[4], lrun[4];
    #pragma unroll
    for (int r = 0; r < 4; ++r) { mrun[r] = -1e30f; lrun[r] = 0.f; }

    __syncthreads();
    stageK(cur, 0);
    stageV(cur, 0);
    __syncthreads();

    for (int kt = 0; kt <= qt; ++kt) {
      if (kt < qt) {
        stageK(cur ^ 1, (kt + 1) * 64);
        stageV(cur ^ 1, (kt + 1) * 64);
      }
      const u16* kl = &Ks[cur][0];
      const u16* vl = &Vs[cur][0];

      f32x4 sc[4] = {};
      __builtin_amdgcn_s_setprio(1);
      #pragma unroll
      for (int ks = 0; ks < 4; ++ks) {
        #pragma unroll
        for (int f = 0; f < 4; ++f) {
          bf16x8 kf = *(const bf16x8*)(kl + (f * 16 + lr) * 128 + (((ks * 4 + lg) ^ swz) * 8));
          sc[f] = __builtin_amdgcn_mfma_f32_16x16x32_bf16(qa[ks], kf, sc[f], 0, 0, 0);
        }
      }
      __builtin_amdgcn_s_setprio(0);
      const bool diag = (kt == qt);
      float p[4][4];
      #pragma unroll
      for (int f = 0; f < 4; ++f)
        #pragma unroll
        for (int r = 0; r < 4; ++r) {
          float v = sc[f][r];
          if (diag && (f * 16 + lr > w * 16 + lg * 4 + r)) v = -1e30f;
          p[f][r] = v;
        }
      float mx[4];
      #pragma unroll
      for (int r = 0; r < 4; ++r) {
        float m0 = fmaxf(fmaxf(p[0][r], p[1][r]), fmaxf(p[2][r], p[3][r]));
        m0 = fmaxf(m0, __shfl_xor(m0, 1));
        m0 = fmaxf(m0, __shfl_xor(m0, 2));
        m0 = fmaxf(m0, __shfl_xor(m0, 4));
        m0 = fmaxf(m0, __shfl_xor(m0, 8));
        mx[r] = m0;
      }
      bool grow = (mx[0] > mrun[0] + 8.f) || (mx[1] > mrun[1] + 8.f) ||
                  (mx[2] > mrun[2] + 8.f) || (mx[3] > mrun[3] + 8.f);
      if (__any(grow)) {
        float resc[4];
        #pragma unroll
        for (int r = 0; r < 4; ++r) {
          float mnew = fmaxf(mrun[r], mx[r]);
          resc[r] = __expf(mrun[r] - mnew);
          mrun[r] = mnew;
          lrun[r] *= resc[r];
        }
        #pragma unroll
        for (int fd = 0; fd < 8; ++fd) {
          f32x4 a = acc[fd];
          a[0] *= resc[0]; a[1] *= resc[1]; a[2] *= resc[2]; a[3] *= resc[3];
          acc[fd] = a;
        }
      }
      #pragma unroll
      for (int r = 0; r < 4; ++r) {
        float sum = 0.f;
        #pragma unroll
        for (int f = 0; f < 4; ++f) {
          float e = __expf(p[f][r] - mrun[r]);
          p[f][r] = e;
          sum += e;
        }
        sum += __shfl_xor(sum, 1);
        sum += __shfl_xor(sum, 2);
        sum += __shfl_xor(sum, 4);
        sum += __shfl_xor(sum, 8);
        lrun[r] += sum;
      }
      {
        const int r0 = lg * 4;
        #pragma unroll
        for (int f = 0; f < 4; ++f) {
          const int col = f * 16 + lr;
          unsigned w01 = cvt_pk_bf16(p[f][0], p[f][1]);
          unsigned w23 = cvt_pk_bf16(p[f][2], p[f][3]);
          pw[(r0 + 0) * 64 + (col ^ (((r0 + 0) & 7) << 3))] = (u16)(w01 & 0xffffu);
          pw[(r0 + 1) * 64 + (col ^ (((r0 + 1) & 7) << 3))] = (u16)(w01 >> 16);
          pw[(r0 + 2) * 64 + (col ^ (((r0 + 2) & 7) << 3))] = (u16)(w23 & 0xffffu);
          pw[(r0 + 3) * 64 + (col ^ (((r0 + 3) & 7) << 3))] = (u16)(w23 >> 16);
        }
      }
      __builtin_amdgcn_s_setprio(1);
      #pragma unroll
      for (int ks = 0; ks < 2; ++ks) {
        int col0 = ks * 32 + lg * 8;
        bf16x8 pa = *(const bf16x8*)(pw + lr * 64 + (col0 ^ (swz << 3)));
        #pragma unroll
        for (int fd = 0; fd < 8; ++fd) {
          bf16x8 vb = *(const bf16x8*)(vl + (fd * 16 + lr) * 64 + (((ks * 4 + lg) ^ swz) * 8));
          acc[fd] = __builtin_amdgcn_mfma_f32_16x16x32_bf16(pa, vb, acc[fd], 0, 0, 0);
        }
      }
      __builtin_amdgcn_s_setprio(0);
      __syncthreads();
      cur ^= 1;
    }

    u16* ob = O + (size_t)(b * S + q0 + lg * 4) * H + h * HD;
    #pragma unroll
    for (int r = 0; r < 4; ++r) {
      float inv = 1.f / lrun[r];
      #pragma unroll
      for (int fd = 0; fd < 8; ++fd)
        ob[(size_t)r * H + fd * 16 + lr] = f2bf(acc[fd][r] * inv);
    }
  }
}

// ---------------- launch ----------------
extern "C" void kernel_launch(void* const* d_in, const int* in_sizes, int n_in,
                              void* d_out, int out_size, void* d_ws, size_t ws_size,
                              hipStream_t stream) {
  const float* x  = (const float*)d_in[0];
  const float* wq = (const float*)d_in[1];
  const float* bq = (const float*)d_in[2];
  const float* wk = (const float*)d_in[3];
  const float* bk = (const float*)d_in[4];
  const float* wv = (const float*)d_in[5];
  const float* bv = (const float*)d_in[6];
  const float* wo = (const float*)d_in[7];
  const float* bo = (const float*)d_in[8];

  char* ws = (char*)d_ws;
  u16*   xb    = (u16*)(ws);                      // 16 MiB  [M][H] bf16
  u16*   wqkvb = (u16*)(ws + (16ull << 20));      // 24 MiB  [6144][2048] (Wq|Wk|Wv)
  u16*   wob   = (u16*)(ws + (40ull << 20));      //  8 MiB
  u16*   Qb    = (u16*)(ws + (48ull << 20));      // 16 MiB
  u16*   Kb    = (u16*)(ws + (64ull << 20));      // 16 MiB
  u16*   Vt    = (u16*)(ws + (80ull << 20));      // 16 MiB [bh][d][s]
  u16*   Ob    = (u16*)(ws + (96ull << 20));      // 16 MiB
  float* tab   = (float*)(ws + (112ull << 20));   //  1 MiB cos/sin
  float* bqkv  = (float*)(ws + (113ull << 20));   // 24 KiB [6144]

  cast_kernel<<<M * H / 1024, 256, 0, stream>>>(x, xb, M * H);
  cast4_kernel<<<dim3(H * H / 1024, 4), 256, 0, stream>>>(
      wq, wk, wv, wo, wqkvb, wqkvb + (size_t)H * H, wqkvb + 2ull * H * H, wob);
  rope_table_k<<<(S * 64 + 255) / 256, 256, 0, stream>>>(tab);
  concat_bias_k<<<24, 256, 0, stream>>>(bq, bk, bv, bqkv);

  gemm_qkv2<<<1536, 256, 0, stream>>>(xb, wqkvb, bqkv, tab, Qb, Kb, Vt);

  attn_fwd<<<512, 256, 0, stream>>>(Qb, Kb, Vt, Ob);

  gemm_o2<<<512, 256, 0, stream>>>(Ob, wob, bo, (float*)d_out);
}